// Round 6
// baseline (9989.535 us; speedup 1.0000x reference)
//
#include <hip/hip_runtime.h>
#include <math.h>
#include <float.h>

#define B_ 128
#define T_ 80
#define D_ 4096
#define H_ 1024
#define V_ 6000
#define VP 6016          // V padded to 128
#define S_ 10
#define G3 (3*H_)
#define KSPLIT 4
#define NBLK 256         // persistent-kernel grid

typedef unsigned short ushort_t;
typedef __attribute__((ext_vector_type(8))) short s16x8;
typedef __attribute__((ext_vector_type(4))) float fx4;

// ---------------- static device scratch ----------------
__device__ float    g_gi[(size_t)B_*T_*G3];        // precomputed x@Wih^T+bih, all t
__device__ ushort_t g_Ah[(size_t)B_*T_*D_];        // data hi (bf16 bits)
__device__ ushort_t g_Al[(size_t)B_*T_*D_];        // data lo
__device__ ushort_t g_Bh[(size_t)G3*D_];           // enc_Wih hi
__device__ ushort_t g_Bl[(size_t)G3*D_];           // enc_Wih lo
__device__ ushort_t g_Whh_h[G3*H_],  g_Whh_l[G3*H_];     // enc_Whh
__device__ ushort_t g_dWih_h[G3*H_], g_dWih_l[G3*H_];    // dec_Wih
__device__ ushort_t g_dWhh_h[G3*H_], g_dWhh_l[G3*H_];    // dec_Whh
__device__ ushort_t g_l1h[H_*2*H_],  g_l1l[H_*2*H_];     // lin1_W (full [H][2H])
__device__ ushort_t g_l2h[(size_t)VP*H_], g_l2l[(size_t)VP*H_]; // lin2_W padded rows
__device__ float g_ghp [KSPLIT*B_*G3];             // split-K partials
__device__ float g_gi2p[KSPLIT*B_*G3];
__device__ float g_gh2p[KSPLIT*B_*G3];
__device__ float g_up  [KSPLIT*B_*H_];
__device__ float g_eh[B_*H_];
__device__ float g_dh[B_*H_];
__device__ ushort_t g_ehh[B_*H_], g_ehl[B_*H_];
__device__ ushort_t g_dhh[B_*H_], g_dhl[B_*H_];
__device__ ushort_t g_uh[B_*H_],  g_ul[B_*H_];
__device__ ushort_t g_cath[B_*2*H_], g_catl[B_*2*H_];
__device__ float g_logitsp[2*B_*VP];
__device__ int   g_word[B_];
__device__ int   g_bar[32];                        // [0]=cnt, [16]=gen

// ---------------- fp32 -> bf16 hi/lo split (RNE) ----------------
__device__ __forceinline__ void split1(float x, ushort_t& hi, ushort_t& lo) {
    unsigned u = __float_as_uint(x);
    unsigned rh = u + 0x7FFF + ((u >> 16) & 1);
    hi = (ushort_t)(rh >> 16);
    float fhi = __uint_as_float((unsigned)hi << 16);
    float d = x - fhi;
    unsigned u2 = __float_as_uint(d);
    unsigned rl = u2 + 0x7FFF + ((u2 >> 16) & 1);
    lo = (ushort_t)(rl >> 16);
}

__global__ __launch_bounds__(256) void split_bf16(
    const float* __restrict__ x, ushort_t* __restrict__ hi,
    ushort_t* __restrict__ lo, int n4)
{
    int i = blockIdx.x * 256 + threadIdx.x;
    if (i >= n4) return;
    float4 v = ((const float4*)x)[i];
    ushort_t h0,h1,h2,h3,l0,l1,l2,l3;
    split1(v.x,h0,l0); split1(v.y,h1,l1); split1(v.z,h2,l2); split1(v.w,h3,l3);
    ushort_t* hp = hi + (size_t)i*4;  hp[0]=h0; hp[1]=h1; hp[2]=h2; hp[3]=h3;
    ushort_t* lp = lo + (size_t)i*4;  lp[0]=l0; lp[1]=l1; lp[2]=l2; lp[3]=l3;
}

// ---------------- async global->LDS 16B ----------------
__device__ __forceinline__ void gld16(const ushort_t* g, void* l) {
    __builtin_amdgcn_global_load_lds(
        (const __attribute__((address_space(1))) void*)(const void*)g,
        (__attribute__((address_space(3))) void*)l, 16, 0, 0);
}

// ---------------- GRU elementwise core ----------------
__device__ __forceinline__ float gru_elem(float ir,float iz,float inn,
                                          float hr,float hz,float hn,float hprev){
    const float r = 1.f/(1.f+expf(-(ir+hr)));
    const float z = 1.f/(1.f+expf(-(iz+hz)));
    const float n = tanhf(inn + r*hn);
    return (1.f-z)*n + z*hprev;
}

// ---------------- standalone bf16x3 MFMA GEMM (precompute + decoder) ----------------
__global__ __launch_bounds__(256) void gemm_x3(
    const ushort_t* __restrict__ Ah, const ushort_t* __restrict__ Al, int lda,
    const ushort_t* __restrict__ Bh, const ushort_t* __restrict__ Bl, int ldw,
    const float* __restrict__ bias,
    float* __restrict__ C,
    int M, int N, int K, int kchunks,
    const ushort_t* __restrict__ A2h, const ushort_t* __restrict__ A2l,
    const ushort_t* __restrict__ B2h, const ushort_t* __restrict__ B2l,
    float* __restrict__ C2)
{
    int z = blockIdx.z;
    int kc = z;
    if (z >= kchunks) { kc = z - kchunks; Ah=A2h; Al=A2l; Bh=B2h; Bl=B2l; C=C2; }

    __shared__ ushort_t sAh[2][128*32], sAl[2][128*32];
    __shared__ ushort_t sBh[2][128*32], sBl[2][128*32];

    const int tid  = threadIdx.x;
    const int bm   = blockIdx.y * 128, bn = blockIdx.x * 128;
    const int wave = tid >> 6, lane = tid & 63;
    const int wr   = (wave >> 1) * 64, wc = (wave & 1) * 64;
    const int r    = lane & 15, g = lane >> 4;

    fx4 acc[4][4] = {};

    const int kper = K / kchunks;
    const int kbeg = kc * kper;
    const int nt   = kper / 32;

#define STAGE(buf, k0)                                                        \
    {                                                                         \
      _Pragma("unroll")                                                       \
      for (int i_ = 0; i_ < 2; ++i_) {                                        \
        const int o_   = (tid + i_*256) * 16;                                 \
        const int row_ = o_ >> 6;                                             \
        const int el_  = (o_ & 63) >> 1;                                      \
        const size_t ga_ = (size_t)(bm + row_) * lda + (k0) + el_;            \
        const size_t gb_ = (size_t)(bn + row_) * ldw + (k0) + el_;            \
        const int lb_ = (wave*64 + i_*256) * 16;                              \
        gld16(Ah + ga_, (char*)&sAh[buf][0] + lb_);                           \
        gld16(Al + ga_, (char*)&sAl[buf][0] + lb_);                           \
        gld16(Bh + gb_, (char*)&sBh[buf][0] + lb_);                           \
        gld16(Bl + gb_, (char*)&sBl[buf][0] + lb_);                           \
      }                                                                       \
    }

    int cur = 0;
    STAGE(0, kbeg)
    __syncthreads();

    for (int t = 0; t < nt; ++t) {
        if (t + 1 < nt) STAGE(cur ^ 1, kbeg + (t+1)*32)

        s16x8 a_h[4], a_l[4], b_h[4], b_l[4];
#pragma unroll
        for (int i = 0; i < 4; ++i) {
            const int ao = (wr + i*16 + r)*32 + g*8;
            const int bo = (wc + i*16 + r)*32 + g*8;
            a_h[i] = *(const s16x8*)&sAh[cur][ao];
            a_l[i] = *(const s16x8*)&sAl[cur][ao];
            b_h[i] = *(const s16x8*)&sBh[cur][bo];
            b_l[i] = *(const s16x8*)&sBl[cur][bo];
        }
#pragma unroll
        for (int i = 0; i < 4; ++i)
#pragma unroll
            for (int j = 0; j < 4; ++j) {
                acc[i][j] = __builtin_amdgcn_mfma_f32_16x16x32_bf16(a_h[i], b_h[j], acc[i][j], 0, 0, 0);
                acc[i][j] = __builtin_amdgcn_mfma_f32_16x16x32_bf16(a_l[i], b_h[j], acc[i][j], 0, 0, 0);
                acc[i][j] = __builtin_amdgcn_mfma_f32_16x16x32_bf16(a_h[i], b_l[j], acc[i][j], 0, 0, 0);
            }
        __syncthreads();
        cur ^= 1;
    }
#undef STAGE

    float* Cw = C + (size_t)kc * M * N;
#pragma unroll
    for (int i = 0; i < 4; ++i)
#pragma unroll
        for (int j = 0; j < 4; ++j)
#pragma unroll
            for (int reg = 0; reg < 4; ++reg) {
                const int row = bm + wr + i*16 + g*4 + reg;
                const int col = bn + wc + j*16 + r;
                float v = acc[i][j][reg];
                if (kchunks == 1 && bias) v += bias[col];
                Cw[(size_t)row * N + col] = v;
            }
}

// ---------------- persistent encoder: weight-stationary jobs ----------------

__device__ __forceinline__ void cwrite(const fx4 (&acc)[4][4],
    float* __restrict__ Cw, int ldc, int colbase, int wr, int wc, int r, int g)
{
#pragma unroll
    for (int i = 0; i < 4; ++i)
#pragma unroll
        for (int j = 0; j < 4; ++j)
#pragma unroll
            for (int reg = 0; reg < 4; ++reg)
                Cw[(size_t)(wr + i*16 + g*4 + reg) * ldc + colbase + wc + j*16 + r]
                    = acc[i][j][reg];
}

// B-phase job: A register-streamed from global (L2-hot), W resident in LDS.
// LDS tile layout: [kt 0..7][row 0..127][kk 0..31] ushort, hi then lo half.
__device__ __forceinline__ void job_resB(
    const ushort_t* __restrict__ Agh, const ushort_t* __restrict__ Agl,
    const ushort_t* __restrict__ sWh, const ushort_t* __restrict__ sWl,
    int kbeg, float* __restrict__ Cw, int ldc, int colbase)
{
    const int tid  = threadIdx.x;
    const int wave = tid >> 6, lane = tid & 63;
    const int wr   = (wave >> 1) * 64, wc = (wave & 1) * 64;
    const int r    = lane & 15, g = lane >> 4;
    fx4 acc[4][4] = {};

    s16x8 a_h[2][4], a_l[2][4];
#pragma unroll
    for (int i = 0; i < 4; ++i) {
        const size_t off = (size_t)(wr + i*16 + r) * H_ + kbeg + g*8;
        a_h[0][i] = *(const s16x8*)(Agh + off);
        a_l[0][i] = *(const s16x8*)(Agl + off);
    }
    for (int kt = 0; kt < 8; ++kt) {
        const int cur = kt & 1, nxt = cur ^ 1;
        if (kt < 7) {
#pragma unroll
            for (int i = 0; i < 4; ++i) {
                const size_t off = (size_t)(wr + i*16 + r) * H_ + kbeg + (kt+1)*32 + g*8;
                a_h[nxt][i] = *(const s16x8*)(Agh + off);
                a_l[nxt][i] = *(const s16x8*)(Agl + off);
            }
        }
        s16x8 b_h[4], b_l[4];
#pragma unroll
        for (int j = 0; j < 4; ++j) {
            const int bo = (kt*128 + (wc + j*16 + r))*32 + g*8;
            b_h[j] = *(const s16x8*)&sWh[bo];
            b_l[j] = *(const s16x8*)&sWl[bo];
        }
#pragma unroll
        for (int i = 0; i < 4; ++i)
#pragma unroll
            for (int j = 0; j < 4; ++j) {
                acc[i][j] = __builtin_amdgcn_mfma_f32_16x16x32_bf16(a_h[cur][i], b_h[j], acc[i][j], 0, 0, 0);
                acc[i][j] = __builtin_amdgcn_mfma_f32_16x16x32_bf16(a_l[cur][i], b_h[j], acc[i][j], 0, 0, 0);
                acc[i][j] = __builtin_amdgcn_mfma_f32_16x16x32_bf16(a_h[cur][i], b_l[j], acc[i][j], 0, 0, 0);
            }
    }
    cwrite(acc, Cw, ldc, colbase, wr, wc, r, g);
}

// C2-phase job: both A and W register-streamed from global (double-buffered).
__device__ __forceinline__ void job_stream(
    const ushort_t* __restrict__ Agh, const ushort_t* __restrict__ Agl,
    const ushort_t* __restrict__ Wgh, const ushort_t* __restrict__ Wgl,  // tile base (row 0 = output col 0)
    int kbeg, float* __restrict__ Cw, int ldc, int colbase)
{
    const int tid  = threadIdx.x;
    const int wave = tid >> 6, lane = tid & 63;
    const int wr   = (wave >> 1) * 64, wc = (wave & 1) * 64;
    const int r    = lane & 15, g = lane >> 4;
    fx4 acc[4][4] = {};

    s16x8 a_h[2][4], a_l[2][4], b_h[2][4], b_l[2][4];
#pragma unroll
    for (int i = 0; i < 4; ++i) {
        const size_t aoff = (size_t)(wr + i*16 + r) * H_ + kbeg + g*8;
        const size_t boff = (size_t)(wc + i*16 + r) * H_ + kbeg + g*8;
        a_h[0][i] = *(const s16x8*)(Agh + aoff);
        a_l[0][i] = *(const s16x8*)(Agl + aoff);
        b_h[0][i] = *(const s16x8*)(Wgh + boff);
        b_l[0][i] = *(const s16x8*)(Wgl + boff);
    }
    for (int kt = 0; kt < 8; ++kt) {
        const int cur = kt & 1, nxt = cur ^ 1;
        if (kt < 7) {
#pragma unroll
            for (int i = 0; i < 4; ++i) {
                const size_t aoff = (size_t)(wr + i*16 + r) * H_ + kbeg + (kt+1)*32 + g*8;
                const size_t boff = (size_t)(wc + i*16 + r) * H_ + kbeg + (kt+1)*32 + g*8;
                a_h[nxt][i] = *(const s16x8*)(Agh + aoff);
                a_l[nxt][i] = *(const s16x8*)(Agl + aoff);
                b_h[nxt][i] = *(const s16x8*)(Wgh + boff);
                b_l[nxt][i] = *(const s16x8*)(Wgl + boff);
            }
        }
#pragma unroll
        for (int i = 0; i < 4; ++i)
#pragma unroll
            for (int j = 0; j < 4; ++j) {
                acc[i][j] = __builtin_amdgcn_mfma_f32_16x16x32_bf16(a_h[cur][i], b_h[cur][j], acc[i][j], 0, 0, 0);
                acc[i][j] = __builtin_amdgcn_mfma_f32_16x16x32_bf16(a_l[cur][i], b_h[cur][j], acc[i][j], 0, 0, 0);
                acc[i][j] = __builtin_amdgcn_mfma_f32_16x16x32_bf16(a_h[cur][i], b_l[cur][j], acc[i][j], 0, 0, 0);
            }
    }
    cwrite(acc, Cw, ldc, colbase, wr, wc, r, g);
}

// grid barrier, agent scope: RELAXED spin + one ACQUIRE after wake (round-5 fix).
__device__ __forceinline__ void gbar(int* cnt, int* gen, int* lg) {
    __syncthreads();
    if (threadIdx.x == 0) {
        const int g = *lg;
        const int prev = __hip_atomic_fetch_add(cnt, 1, __ATOMIC_ACQ_REL,
                                                __HIP_MEMORY_SCOPE_AGENT);
        if (prev == NBLK - 1) {
            __hip_atomic_store(cnt, 0, __ATOMIC_RELAXED, __HIP_MEMORY_SCOPE_AGENT);
            __hip_atomic_store(gen, g + 1, __ATOMIC_RELEASE, __HIP_MEMORY_SCOPE_AGENT);
        } else {
            while (__hip_atomic_load(gen, __ATOMIC_RELAXED,
                                     __HIP_MEMORY_SCOPE_AGENT) == g)
                __builtin_amdgcn_s_sleep(8);
            (void)__hip_atomic_load(gen, __ATOMIC_ACQUIRE,
                                    __HIP_MEMORY_SCOPE_AGENT);
        }
        *lg = g + 1;
    }
    __syncthreads();
}

__device__ __forceinline__ void dec_update(int idx,
    const float* __restrict__ gi2p, const float* __restrict__ gh2p,
    const float* __restrict__ dec_bih, const float* __restrict__ dec_bhh,
    float* __restrict__ dh, ushort_t* __restrict__ dhh, ushort_t* __restrict__ dhl)
{
    const int b = idx >> 10, j = idx & (H_ - 1);
    float ir = dec_bih[j], iz = dec_bih[H_+j], inn = dec_bih[2*H_+j];
    const float* p = gi2p + (size_t)b * G3;
#pragma unroll
    for (int s2 = 0; s2 < KSPLIT; ++s2) {
        ir += p[j]; iz += p[H_+j]; inn += p[2*H_+j];
        p += (size_t)B_ * G3;
    }
    float hr = dec_bhh[j], hz = dec_bhh[H_+j], hn = dec_bhh[2*H_+j];
    const float* q = gh2p + (size_t)b * G3;
#pragma unroll
    for (int s2 = 0; s2 < KSPLIT; ++s2) {
        hr += q[j]; hz += q[H_+j]; hn += q[2*H_+j];
        q += (size_t)B_ * G3;
    }
    const float v = gru_elem(ir, iz, inn, hr, hz, hn, dh[idx]);
    dh[idx] = v;
    split1(v, dhh[idx], dhl[idx]);
}

// ---------------- persistent weight-stationary encoder scan ----------------
__global__ __launch_bounds__(256) void enc_persist(
    const float* __restrict__ gi,
    const ushort_t* __restrict__ Whh_h, const ushort_t* __restrict__ Whh_l,
    const ushort_t* __restrict__ l1h,   const ushort_t* __restrict__ l1l,
    const ushort_t* __restrict__ dWih_h,const ushort_t* __restrict__ dWih_l,
    const ushort_t* __restrict__ dWhh_h,const ushort_t* __restrict__ dWhh_l,
    const float* __restrict__ enc_bhh,  const float* __restrict__ lin1_b,
    const float* __restrict__ dec_bih,  const float* __restrict__ dec_bhh,
    float* __restrict__ eh, ushort_t* __restrict__ ehh, ushort_t* __restrict__ ehl,
    float* __restrict__ dh, ushort_t* __restrict__ dhh, ushort_t* __restrict__ dhl,
    ushort_t* __restrict__ uh, ushort_t* __restrict__ ul,
    float* __restrict__ ghp, float* __restrict__ up,
    float* __restrict__ gi2p, float* __restrict__ gh2p,
    int* __restrict__ bar)
{
    extern __shared__ ushort_t smw[];     // 128 KiB: [0,32768) hi, [32768,65536) lo
    ushort_t* sWh = smw;
    ushort_t* sWl = smw + 32768;

    const int bid = blockIdx.x;
    const int tid = threadIdx.x;
    int* cnt = &bar[0];
    int* gen = &bar[16];
    int lg = 0;

    // ---- one-time: load this block's resident B-phase weight tile into LDS ----
    // job map (identical to phase-B dispatch below):
    //   bid   0..95 : Whh  tile (ntile=bid>>2 of 24, kc=bid&3)           ldw=H_
    //   bid  96..127: l1a  tile (ntile=(bid-96)>>2 of 8, kc=(bid-96)&3)  ldw=2H_
    //   bid 128..223: dWhh tile (ntile=(bid-128)>>2 of 24, kc=(bid-128)&3) ldw=H_
    if (bid < 224) {
        const ushort_t *Wh, *Wl; int ldw, rowbase, kbeg0;
        if (bid < 96)       { const int jj=bid;     Wh=Whh_h;  Wl=Whh_l;  ldw=H_;   rowbase=(jj>>2)*128; kbeg0=(jj&3)*256; }
        else if (bid < 128) { const int jj=bid-96;  Wh=l1h;    Wl=l1l;    ldw=2*H_; rowbase=(jj>>2)*128; kbeg0=(jj&3)*256; }
        else                { const int jj=bid-128; Wh=dWhh_h; Wl=dWhh_l; ldw=H_;   rowbase=(jj>>2)*128; kbeg0=(jj&3)*256; }
        for (int c = tid; c < 4096; c += 256) {      // 4096 chunks of 8 ushorts
            const int row  = c >> 5;
            const int col8 = (c & 31) * 8;
            const int kt = col8 >> 5, kk = col8 & 31;
            const size_t goff = (size_t)(rowbase + row) * ldw + kbeg0 + col8;
            const int    loff = (kt*128 + row)*32 + kk;
            *(s16x8*)&sWh[loff] = *(const s16x8*)(Wh + goff);
            *(s16x8*)&sWl[loff] = *(const s16x8*)(Wl + goff);
        }
    }
    __syncthreads();

    for (int t = 0; t < T_; ++t) {
        // ---- phase A: eh <- GRU(gi[t], ghp) ; dh <- GRU(gi2p, gh2p) [step t-1] ----
#pragma unroll
        for (int rep = 0; rep < 2; ++rep) {
            const int idx = bid * 512 + rep * 256 + tid;     // covers B_*H_
            const int b = idx >> 10, j = idx & (H_ - 1);
            const float* girow = gi + ((size_t)(b * T_ + t)) * G3;
            float ir = girow[j], iz = girow[H_+j], inn = girow[2*H_+j];
            float hr = enc_bhh[j], hz = enc_bhh[H_+j], hn = enc_bhh[2*H_+j];
            const float* q = ghp + (size_t)b * G3;
#pragma unroll
            for (int s2 = 0; s2 < KSPLIT; ++s2) {
                hr += q[j]; hz += q[H_+j]; hn += q[2*H_+j];
                q += (size_t)B_ * G3;
            }
            const float v = gru_elem(ir, iz, inn, hr, hz, hn, eh[idx]);
            eh[idx] = v;
            split1(v, ehh[idx], ehl[idx]);
            if (t > 0)
                dec_update(idx, gi2p, gh2p, dec_bih, dec_bhh, dh, dhh, dhl);
        }
        gbar(cnt, gen, &lg);

        // ---- phase B (resident weights): ghp / up / gh2p ----
        if (bid < 96) {
            const int ntile = bid >> 2, kc = bid & 3;
            job_resB(ehh, ehl, sWh, sWl, kc*256,
                     ghp + (size_t)kc * B_ * G3, G3, ntile * 128);
        } else if (bid < 128) {
            const int jj = bid - 96, ntile = jj >> 2, kc = jj & 3;
            job_resB(ehh, ehl, sWh, sWl, kc*256,
                     up + (size_t)kc * B_ * H_, H_, ntile * 128);
        } else if (bid < 224) {
            const int jj = bid - 128, ntile = jj >> 2, kc = jj & 3;
            job_resB(dhh, dhl, sWh, sWl, kc*256,
                     gh2p + (size_t)kc * B_ * G3, G3, ntile * 128);
        }
        gbar(cnt, gen, &lg);

        // ---- phase C1: u <- relu(sum up + lin1_b), split ----
#pragma unroll
        for (int rep = 0; rep < 2; ++rep) {
            const int idx = bid * 512 + rep * 256 + tid;
            const int j = idx & (H_ - 1);
            float v = lin1_b[j];
#pragma unroll
            for (int s2 = 0; s2 < KSPLIT; ++s2) v += up[(size_t)s2 * B_ * H_ + idx];
            v = fmaxf(v, 0.f);
            split1(v, uh[idx], ul[idx]);
        }
        gbar(cnt, gen, &lg);

        // ---- phase C2 (streamed dWih): gi2p <- u@dWih^T ----
        if (bid < 96) {
            const int ntile = bid >> 2, kc = bid & 3;
            job_stream(uh, ul,
                       dWih_h + (size_t)ntile * 128 * H_,
                       dWih_l + (size_t)ntile * 128 * H_,
                       kc * 256,
                       gi2p + (size_t)kc * B_ * G3, G3, ntile * 128);
        }
        gbar(cnt, gen, &lg);
    }

    // tail: finish dec GRU of step T-1
#pragma unroll
    for (int rep = 0; rep < 2; ++rep) {
        const int idx = bid * 512 + rep * 256 + tid;
        dec_update(idx, gi2p, gh2p, dec_bih, dec_bhh, dh, dhh, dhl);
    }
}

// ---------------- decoder elementwise kernels ----------------
__global__ __launch_bounds__(256) void gru_update2(
    const float* __restrict__ GI, int gi_rstride, int gi_nsplit,
    const float* __restrict__ bih,
    const float* __restrict__ GHp, const float* __restrict__ bhh,
    float* __restrict__ h, ushort_t* __restrict__ hh, ushort_t* __restrict__ hl)
{
    const int idx = blockIdx.x * 256 + threadIdx.x;
    const int b = idx >> 10;
    const int j = idx & (H_ - 1);
    float ir, iz, inn;
    if (gi_nsplit == 0) {
        const float* gi = GI + (size_t)b * gi_rstride;
        ir = gi[j]; iz = gi[H_ + j]; inn = gi[2*H_ + j];
    } else {
        ir = bih[j]; iz = bih[H_ + j]; inn = bih[2*H_ + j];
        const float* p = GI + (size_t)b * G3;
#pragma unroll
        for (int s = 0; s < KSPLIT; ++s) {
            ir += p[j]; iz += p[H_ + j]; inn += p[2*H_ + j];
            p += (size_t)B_ * G3;
        }
    }
    float hr = bhh[j], hz = bhh[H_ + j], hn = bhh[2*H_ + j];
    const float* q = GHp + (size_t)b * G3;
#pragma unroll
    for (int s = 0; s < KSPLIT; ++s) {
        hr += q[j]; hz += q[H_ + j]; hn += q[2*H_ + j];
        q += (size_t)B_ * G3;
    }
    const float v = gru_elem(ir, iz, inn, hr, hz, hn, h[idx]);
    h[idx] = v;
    split1(v, hh[idx], hl[idx]);
}

__global__ __launch_bounds__(256) void relu_combine(
    const float* __restrict__ Up, const float* __restrict__ bias,
    ushort_t* __restrict__ uh, ushort_t* __restrict__ ul)
{
    const int idx = blockIdx.x * 256 + threadIdx.x;
    const int j = idx & (H_ - 1);
    float v = bias[j];
#pragma unroll
    for (int s = 0; s < KSPLIT; ++s) v += Up[(size_t)s * B_ * H_ + idx];
    v = fmaxf(v, 0.f);
    split1(v, uh[idx], ul[idx]);
}

__global__ __launch_bounds__(256) void cat_eh_emb(
    const ushort_t* __restrict__ ehh, const ushort_t* __restrict__ ehl,
    const float* __restrict__ embed, const int* __restrict__ word,
    ushort_t* __restrict__ cath, ushort_t* __restrict__ catl)
{
    const int idx = blockIdx.x * 256 + threadIdx.x;
    const int b = idx >> 11;
    const int j = idx & (2*H_ - 1);
    if (j < H_) {
        cath[idx] = ehh[b * H_ + j];
        catl[idx] = ehl[b * H_ + j];
    } else {
        float v = embed[(size_t)word[b] * H_ + (j - H_)];
        split1(v, cath[idx], catl[idx]);
    }
}

// ---------------- init (also zeroes ghp + barrier) ----------------
__global__ __launch_bounds__(256) void init_state(
    float* __restrict__ eh, float* __restrict__ dh,
    ushort_t* __restrict__ ehh, ushort_t* __restrict__ ehl,
    ushort_t* __restrict__ dhh, ushort_t* __restrict__ dhl,
    int* __restrict__ word, float* __restrict__ out,
    float* __restrict__ ghp, int* __restrict__ bar)
{
    const int idx = blockIdx.x * 256 + threadIdx.x;
    if (idx < KSPLIT*B_*G3) ghp[idx] = 0.f;
    if (idx < B_*H_) {
        eh[idx] = 0.f; dh[idx] = 0.f;
        ehh[idx] = 0; ehl[idx] = 0; dhh[idx] = 0; dhl[idx] = 0;
    }
    if (idx < B_)  word[idx] = 1;
    if (idx < 21)  out[idx] = 0.f;
    if (idx < 32)  bar[idx] = 0;
}

// ---------------- log-softmax + argmax + loss over 2 logit partials ----------------
__global__ __launch_bounds__(256) void softmax_loss(
    const float* __restrict__ logp, const float* __restrict__ l2b,
    const int* __restrict__ target, int s, int* __restrict__ word,
    float* __restrict__ out)
{
    const int b = blockIdx.x;
    const int t = threadIdx.x;
    const float* p0 = logp + (size_t)b * VP;
    const float* p1 = p0 + (size_t)B_ * VP;
    __shared__ float sv[256];
    __shared__ int   si[256];
    __shared__ float ss[256];

    float best = -FLT_MAX; int bi = 0;
    for (int j = t; j < V_; j += 256) {
        float v = p0[j] + p1[j] + l2b[j];
        if (v > best) { best = v; bi = j; }
    }
    sv[t] = best; si[t] = bi;
    __syncthreads();
    for (int off = 128; off > 0; off >>= 1) {
        if (t < off) {
            float v2 = sv[t + off]; int i2 = si[t + off];
            if (v2 > sv[t] || (v2 == sv[t] && i2 < si[t])) { sv[t] = v2; si[t] = i2; }
        }
        __syncthreads();
    }
    const float m = sv[0];
    const int amax = si[0];

    float sum = 0.f;
    for (int j = t; j < V_; j += 256) sum += expf(p0[j] + p1[j] + l2b[j] - m);
    ss[t] = sum;
    __syncthreads();
    for (int off = 128; off > 0; off >>= 1) {
        if (t < off) ss[t] += ss[t + off];
        __syncthreads();
    }
    if (t == 0) {
        const float lse = m + logf(ss[0]);
        const int tgt = target[b * S_ + s];
        const float logit_t = p0[tgt] + p1[tgt] + l2b[tgt];
        atomicAdd(&out[0], -(logit_t - lse) * (1.0f / (float)B_));
        word[b] = amax;
        if (b == 0) out[1 + s]  = (float)amax;
        if (b == 1) out[11 + s] = (float)amax;
    }
}

// ---------------- host helpers ----------------
static inline void launch_x3(hipStream_t st,
    const ushort_t* Ah, const ushort_t* Al, int lda,
    const ushort_t* Bh, const ushort_t* Bl, int ldw,
    const float* bias, float* C, int M, int N, int K, int kchunks)
{
    dim3 grid(N/128, M/128, kchunks);
    gemm_x3<<<grid, 256, 0, st>>>(Ah, Al, lda, Bh, Bl, ldw, bias, C, M, N, K, kchunks,
                                  nullptr, nullptr, nullptr, nullptr, nullptr);
}

static inline void launch_x3_dual(hipStream_t st,
    const ushort_t* Ah, const ushort_t* Al,
    const ushort_t* Bh, const ushort_t* Bl, float* C,
    const ushort_t* A2h, const ushort_t* A2l,
    const ushort_t* B2h, const ushort_t* B2l, float* C2,
    int M, int N, int K, int kchunks)
{
    dim3 grid(N/128, M/128, 2*kchunks);
    gemm_x3<<<grid, 256, 0, st>>>(Ah, Al, H_, Bh, Bl, H_, nullptr, C, M, N, K, kchunks,
                                  A2h, A2l, B2h, B2l, C2);
}

extern "C" void kernel_launch(void* const* d_in, const int* in_sizes, int n_in,
                              void* d_out, int out_size, void* d_ws, size_t ws_size,
                              hipStream_t stream)
{
    const float* data    = (const float*)d_in[0];
    const int*   target  = (const int*)  d_in[2];
    const float* enc_Wih = (const float*)d_in[4];
    const float* enc_Whh = (const float*)d_in[5];
    const float* enc_bih = (const float*)d_in[6];
    const float* enc_bhh = (const float*)d_in[7];
    const float* dec_Wih = (const float*)d_in[8];
    const float* dec_Whh = (const float*)d_in[9];
    const float* dec_bih = (const float*)d_in[10];
    const float* dec_bhh = (const float*)d_in[11];
    const float* lin1_W  = (const float*)d_in[12];
    const float* lin1_b  = (const float*)d_in[13];
    const float* lin2_W  = (const float*)d_in[14];
    const float* lin2_b  = (const float*)d_in[15];
    const float* embed   = (const float*)d_in[16];
    float* out = (float*)d_out;

    float *gi, *eh, *dh, *logitsp, *ghp, *gi2p, *gh2p, *up;
    ushort_t *Ah, *Al, *Bh, *Bl, *Whh_h, *Whh_l, *dWih_h, *dWih_l, *dWhh_h, *dWhh_l;
    ushort_t *l1h, *l1l, *l2h, *l2l, *ehh, *ehl, *dhh, *dhl, *uh, *ul, *cath, *catl;
    int *word, *bar;
    hipGetSymbolAddress((void**)&gi,     HIP_SYMBOL(g_gi));
    hipGetSymbolAddress((void**)&Ah,     HIP_SYMBOL(g_Ah));
    hipGetSymbolAddress((void**)&Al,     HIP_SYMBOL(g_Al));
    hipGetSymbolAddress((void**)&Bh,     HIP_SYMBOL(g_Bh));
    hipGetSymbolAddress((void**)&Bl,     HIP_SYMBOL(g_Bl));
    hipGetSymbolAddress((void**)&Whh_h,  HIP_SYMBOL(g_Whh_h));
    hipGetSymbolAddress((void**)&Whh_l,  HIP_SYMBOL(g_Whh_l));
    hipGetSymbolAddress((void**)&dWih_h, HIP_SYMBOL(g_dWih_h));
    hipGetSymbolAddress((void**)&dWih_l, HIP_SYMBOL(g_dWih_l));
    hipGetSymbolAddress((void**)&dWhh_h, HIP_SYMBOL(g_dWhh_h));
    hipGetSymbolAddress((void**)&dWhh_l, HIP_SYMBOL(g_dWhh_l));
    hipGetSymbolAddress((void**)&l1h,    HIP_SYMBOL(g_l1h));
    hipGetSymbolAddress((void**)&l1l,    HIP_SYMBOL(g_l1l));
    hipGetSymbolAddress((void**)&l2h,    HIP_SYMBOL(g_l2h));
    hipGetSymbolAddress((void**)&l2l,    HIP_SYMBOL(g_l2l));
    hipGetSymbolAddress((void**)&ghp,    HIP_SYMBOL(g_ghp));
    hipGetSymbolAddress((void**)&gi2p,   HIP_SYMBOL(g_gi2p));
    hipGetSymbolAddress((void**)&gh2p,   HIP_SYMBOL(g_gh2p));
    hipGetSymbolAddress((void**)&up,     HIP_SYMBOL(g_up));
    hipGetSymbolAddress((void**)&eh,     HIP_SYMBOL(g_eh));
    hipGetSymbolAddress((void**)&dh,     HIP_SYMBOL(g_dh));
    hipGetSymbolAddress((void**)&ehh,    HIP_SYMBOL(g_ehh));
    hipGetSymbolAddress((void**)&ehl,    HIP_SYMBOL(g_ehl));
    hipGetSymbolAddress((void**)&dhh,    HIP_SYMBOL(g_dhh));
    hipGetSymbolAddress((void**)&dhl,    HIP_SYMBOL(g_dhl));
    hipGetSymbolAddress((void**)&uh,     HIP_SYMBOL(g_uh));
    hipGetSymbolAddress((void**)&ul,     HIP_SYMBOL(g_ul));
    hipGetSymbolAddress((void**)&cath,   HIP_SYMBOL(g_cath));
    hipGetSymbolAddress((void**)&catl,   HIP_SYMBOL(g_catl));
    hipGetSymbolAddress((void**)&logitsp,HIP_SYMBOL(g_logitsp));
    hipGetSymbolAddress((void**)&word,   HIP_SYMBOL(g_word));
    hipGetSymbolAddress((void**)&bar,    HIP_SYMBOL(g_bar));

    // allow 128 KiB dynamic LDS for the weight-stationary encoder
    hipFuncSetAttribute((const void*)enc_persist,
                        hipFuncAttributeMaxDynamicSharedMemorySize, 131072);

    init_state<<<6144, 256, 0, stream>>>(eh, dh, ehh, ehl, dhh, dhl, word, out, ghp, bar);

    // bf16 hi/lo splits
    split_bf16<<<(B_*T_*D_/4 + 255)/256, 256, 0, stream>>>(data,    Ah, Al, B_*T_*D_/4);
    split_bf16<<<(G3*D_/4   + 255)/256, 256, 0, stream>>>(enc_Wih, Bh, Bl, G3*D_/4);
    split_bf16<<<(G3*H_/4   + 255)/256, 256, 0, stream>>>(enc_Whh, Whh_h, Whh_l, G3*H_/4);
    split_bf16<<<(G3*H_/4   + 255)/256, 256, 0, stream>>>(dec_Wih, dWih_h, dWih_l, G3*H_/4);
    split_bf16<<<(G3*H_/4   + 255)/256, 256, 0, stream>>>(dec_Whh, dWhh_h, dWhh_l, G3*H_/4);
    split_bf16<<<(H_*2*H_/4 + 255)/256, 256, 0, stream>>>(lin1_W,  l1h, l1l, H_*2*H_/4);
    split_bf16<<<(V_*H_/4   + 255)/256, 256, 0, stream>>>(lin2_W,  l2h, l2l, V_*H_/4);

    // gi[B*T][3H] = data @ enc_Wih^T + enc_bih
    launch_x3(stream, Ah, Al, D_, Bh, Bl, D_, enc_bih, gi, B_*T_, G3, D_, 1);

    // ---------------- encoder scan: ONE persistent weight-stationary launch ----------------
    enc_persist<<<NBLK, 256, 131072, stream>>>(
        gi, Whh_h, Whh_l, l1h, l1l, dWih_h, dWih_l, dWhh_h, dWhh_l,
        enc_bhh, lin1_b, dec_bih, dec_bhh,
        eh, ehh, ehl, dh, dhh, dhl, uh, ul,
        ghp, up, gi2p, gh2p, bar);

    // ---------------- decoder scan ----------------
    for (int s = 0; s < S_; ++s) {
        launch_x3(stream, ehh, ehl, H_, Whh_h, Whh_l, H_, nullptr, ghp, B_, G3, H_, KSPLIT);
        gru_update2<<<512, 256, 0, stream>>>(enc_bih, 0, 0, nullptr,
                                             ghp, enc_bhh, eh, ehh, ehl);
        cat_eh_emb<<<1024, 256, 0, stream>>>(ehh, ehl, embed, word, cath, catl);
        launch_x3(stream, cath, catl, 2*H_, l1h, l1l, 2*H_, nullptr, up, B_, H_, 2*H_, KSPLIT);
        relu_combine<<<512, 256, 0, stream>>>(up, lin1_b, uh, ul);
        launch_x3_dual(stream, uh, ul, dWih_h, dWih_l, gi2p,
                               dhh, dhl, dWhh_h, dWhh_l, gh2p, B_, G3, H_, KSPLIT);
        gru_update2<<<512, 256, 0, stream>>>(gi2p, 0, KSPLIT, dec_bih,
                                             gh2p, dec_bhh, dh, dhh, dhl);
        launch_x3(stream, dhh, dhl, H_, l2h, l2l, H_, nullptr, logitsp, B_, VP, H_, 2);
        softmax_loss<<<B_, 256, 0, stream>>>(logitsp, lin2_b, target, s, word, out);
    }
}

// Round 7
// 8786.230 us; speedup vs baseline: 1.1370x; 1.1370x over previous
//
#include <hip/hip_runtime.h>
#include <math.h>
#include <float.h>

#define B_ 128
#define T_ 80
#define D_ 4096
#define H_ 1024
#define V_ 6000
#define VP 6016          // V padded to 128
#define S_ 10
#define G3 (3*H_)
#define KSPLIT 4
#define NBLK 256         // persistent-kernel grid
#define BAR_MASTER 320
#define BAR_GEN    336

typedef unsigned short ushort_t;
typedef unsigned long long ull_t;
typedef __attribute__((ext_vector_type(8))) short s16x8;
typedef __attribute__((ext_vector_type(4))) float fx4;

// ---------------- static device scratch ----------------
__device__ float    g_gi[(size_t)B_*T_*G3];        // precomputed x@Wih^T+bih, all t
__device__ ushort_t g_Ah[(size_t)B_*T_*D_];        // data hi (bf16 bits)
__device__ ushort_t g_Al[(size_t)B_*T_*D_];        // data lo
__device__ ushort_t g_Bh[(size_t)G3*D_];           // enc_Wih hi
__device__ ushort_t g_Bl[(size_t)G3*D_];           // enc_Wih lo
__device__ ushort_t g_Whh_h[G3*H_],  g_Whh_l[G3*H_];     // enc_Whh
__device__ ushort_t g_dWih_h[G3*H_], g_dWih_l[G3*H_];    // dec_Wih
__device__ ushort_t g_dWhh_h[G3*H_], g_dWhh_l[G3*H_];    // dec_Whh
__device__ ushort_t g_l1h[H_*2*H_],  g_l1l[H_*2*H_];     // lin1_W (full [H][2H])
__device__ ushort_t g_l2h[(size_t)VP*H_], g_l2l[(size_t)VP*H_]; // lin2_W padded rows
__device__ float g_ghp [KSPLIT*B_*G3];             // split-K partials
__device__ float g_gi2p[KSPLIT*B_*G3];
__device__ float g_gh2p[KSPLIT*B_*G3];
__device__ float g_up  [KSPLIT*B_*H_];
__device__ float g_eh[B_*H_];
__device__ float g_dh[B_*H_];
__device__ ushort_t g_ehh[B_*H_], g_ehl[B_*H_];
__device__ ushort_t g_dhh[B_*H_], g_dhl[B_*H_];
__device__ ushort_t g_uh[B_*H_],  g_ul[B_*H_];
__device__ ushort_t g_cath[B_*2*H_], g_catl[B_*2*H_];
__device__ float g_logitsp[2*B_*VP];
__device__ int   g_word[B_];
__device__ int   g_bar[512];   // [g*16] group counters (16), [320] master, [336] gen

// ---------------- coherent (L2-bypass, sc1) helpers: relaxed agent atomics ----------------
__device__ __forceinline__ ull_t ald64(const void* p) {
    return __hip_atomic_load((const ull_t*)p, __ATOMIC_RELAXED, __HIP_MEMORY_SCOPE_AGENT);
}
__device__ __forceinline__ void ast64(void* p, ull_t v) {
    __hip_atomic_store((ull_t*)p, v, __ATOMIC_RELAXED, __HIP_MEMORY_SCOPE_AGENT);
}
__device__ __forceinline__ unsigned ald32(const void* p) {
    return __hip_atomic_load((const unsigned*)p, __ATOMIC_RELAXED, __HIP_MEMORY_SCOPE_AGENT);
}
__device__ __forceinline__ void ast32(void* p, unsigned v) {
    __hip_atomic_store((unsigned*)p, v, __ATOMIC_RELAXED, __HIP_MEMORY_SCOPE_AGENT);
}
__device__ __forceinline__ void astf(float* p, float v) {
    ast32(p, __float_as_uint(v));
}
__device__ __forceinline__ float2 u2f2(ull_t v) {
    union { ull_t u; float2 f; } x; x.u = v; return x.f;
}
__device__ __forceinline__ s16x8 ald_s16x8(const ushort_t* p) {
    union { ull_t q[2]; s16x8 v; } u;
    u.q[0] = ald64(p); u.q[1] = ald64(p + 4);
    return u.v;
}

// ---------------- fp32 -> bf16 hi/lo split (RNE) ----------------
__device__ __forceinline__ void split1(float x, ushort_t& hi, ushort_t& lo) {
    unsigned u = __float_as_uint(x);
    unsigned rh = u + 0x7FFF + ((u >> 16) & 1);
    hi = (ushort_t)(rh >> 16);
    float fhi = __uint_as_float((unsigned)hi << 16);
    float d = x - fhi;
    unsigned u2 = __float_as_uint(d);
    unsigned rl = u2 + 0x7FFF + ((u2 >> 16) & 1);
    lo = (ushort_t)(rl >> 16);
}

__global__ __launch_bounds__(256) void split_bf16(
    const float* __restrict__ x, ushort_t* __restrict__ hi,
    ushort_t* __restrict__ lo, int n4)
{
    int i = blockIdx.x * 256 + threadIdx.x;
    if (i >= n4) return;
    float4 v = ((const float4*)x)[i];
    ushort_t h0,h1,h2,h3,l0,l1,l2,l3;
    split1(v.x,h0,l0); split1(v.y,h1,l1); split1(v.z,h2,l2); split1(v.w,h3,l3);
    ushort_t* hp = hi + (size_t)i*4;  hp[0]=h0; hp[1]=h1; hp[2]=h2; hp[3]=h3;
    ushort_t* lp = lo + (size_t)i*4;  lp[0]=l0; lp[1]=l1; lp[2]=l2; lp[3]=l3;
}

// ---------------- async global->LDS 16B ----------------
__device__ __forceinline__ void gld16(const ushort_t* g, void* l) {
    __builtin_amdgcn_global_load_lds(
        (const __attribute__((address_space(1))) void*)(const void*)g,
        (__attribute__((address_space(3))) void*)l, 16, 0, 0);
}

// ---------------- GRU elementwise core ----------------
__device__ __forceinline__ float gru_elem(float ir,float iz,float inn,
                                          float hr,float hz,float hn,float hprev){
    const float r = 1.f/(1.f+expf(-(ir+hr)));
    const float z = 1.f/(1.f+expf(-(iz+hz)));
    const float n = tanhf(inn + r*hn);
    return (1.f-z)*n + z*hprev;
}

// ---------------- standalone bf16x3 MFMA GEMM (precompute + decoder) ----------------
__global__ __launch_bounds__(256) void gemm_x3(
    const ushort_t* __restrict__ Ah, const ushort_t* __restrict__ Al, int lda,
    const ushort_t* __restrict__ Bh, const ushort_t* __restrict__ Bl, int ldw,
    const float* __restrict__ bias,
    float* __restrict__ C,
    int M, int N, int K, int kchunks,
    const ushort_t* __restrict__ A2h, const ushort_t* __restrict__ A2l,
    const ushort_t* __restrict__ B2h, const ushort_t* __restrict__ B2l,
    float* __restrict__ C2)
{
    int z = blockIdx.z;
    int kc = z;
    if (z >= kchunks) { kc = z - kchunks; Ah=A2h; Al=A2l; Bh=B2h; Bl=B2l; C=C2; }

    __shared__ ushort_t sAh[2][128*32], sAl[2][128*32];
    __shared__ ushort_t sBh[2][128*32], sBl[2][128*32];

    const int tid  = threadIdx.x;
    const int bm   = blockIdx.y * 128, bn = blockIdx.x * 128;
    const int wave = tid >> 6, lane = tid & 63;
    const int wr   = (wave >> 1) * 64, wc = (wave & 1) * 64;
    const int r    = lane & 15, g = lane >> 4;

    fx4 acc[4][4] = {};

    const int kper = K / kchunks;
    const int kbeg = kc * kper;
    const int nt   = kper / 32;

#define STAGE(buf, k0)                                                        \
    {                                                                         \
      _Pragma("unroll")                                                       \
      for (int i_ = 0; i_ < 2; ++i_) {                                        \
        const int o_   = (tid + i_*256) * 16;                                 \
        const int row_ = o_ >> 6;                                             \
        const int el_  = (o_ & 63) >> 1;                                      \
        const size_t ga_ = (size_t)(bm + row_) * lda + (k0) + el_;            \
        const size_t gb_ = (size_t)(bn + row_) * ldw + (k0) + el_;            \
        const int lb_ = (wave*64 + i_*256) * 16;                              \
        gld16(Ah + ga_, (char*)&sAh[buf][0] + lb_);                           \
        gld16(Al + ga_, (char*)&sAl[buf][0] + lb_);                           \
        gld16(Bh + gb_, (char*)&sBh[buf][0] + lb_);                           \
        gld16(Bl + gb_, (char*)&sBl[buf][0] + lb_);                           \
      }                                                                       \
    }

    int cur = 0;
    STAGE(0, kbeg)
    __syncthreads();

    for (int t = 0; t < nt; ++t) {
        if (t + 1 < nt) STAGE(cur ^ 1, kbeg + (t+1)*32)

        s16x8 a_h[4], a_l[4], b_h[4], b_l[4];
#pragma unroll
        for (int i = 0; i < 4; ++i) {
            const int ao = (wr + i*16 + r)*32 + g*8;
            const int bo = (wc + i*16 + r)*32 + g*8;
            a_h[i] = *(const s16x8*)&sAh[cur][ao];
            a_l[i] = *(const s16x8*)&sAl[cur][ao];
            b_h[i] = *(const s16x8*)&sBh[cur][bo];
            b_l[i] = *(const s16x8*)&sBl[cur][bo];
        }
#pragma unroll
        for (int i = 0; i < 4; ++i)
#pragma unroll
            for (int j = 0; j < 4; ++j) {
                acc[i][j] = __builtin_amdgcn_mfma_f32_16x16x32_bf16(a_h[i], b_h[j], acc[i][j], 0, 0, 0);
                acc[i][j] = __builtin_amdgcn_mfma_f32_16x16x32_bf16(a_l[i], b_h[j], acc[i][j], 0, 0, 0);
                acc[i][j] = __builtin_amdgcn_mfma_f32_16x16x32_bf16(a_h[i], b_l[j], acc[i][j], 0, 0, 0);
            }
        __syncthreads();
        cur ^= 1;
    }
#undef STAGE

    float* Cw = C + (size_t)kc * M * N;
#pragma unroll
    for (int i = 0; i < 4; ++i)
#pragma unroll
        for (int j = 0; j < 4; ++j)
#pragma unroll
            for (int reg = 0; reg < 4; ++reg) {
                const int row = bm + wr + i*16 + g*4 + reg;
                const int col = bn + wc + j*16 + r;
                float v = acc[i][j][reg];
                if (kchunks == 1 && bias) v += bias[col];
                Cw[(size_t)row * N + col] = v;
            }
}

// ---------------- persistent encoder: jobs ----------------

// partial C-write through L2 (sc1) so consumers need no invalidate
__device__ __forceinline__ void cwrite_at(const fx4 (&acc)[4][4],
    float* __restrict__ Cw, int ldc, int colbase, int wr, int wc, int r, int g)
{
#pragma unroll
    for (int i = 0; i < 4; ++i)
#pragma unroll
        for (int j = 0; j < 4; ++j)
#pragma unroll
            for (int reg = 0; reg < 4; ++reg)
                astf(&Cw[(size_t)(wr + i*16 + g*4 + reg) * ldc + colbase + wc + j*16 + r],
                     acc[i][j][reg]);
}

// B-phase job: A (activations) via sc1 loads, W resident in LDS.
__device__ __forceinline__ void job_resB(
    const ushort_t* __restrict__ Agh, const ushort_t* __restrict__ Agl,
    const ushort_t* __restrict__ sWh, const ushort_t* __restrict__ sWl,
    int kbeg, float* __restrict__ Cw, int ldc, int colbase)
{
    const int tid  = threadIdx.x;
    const int wave = tid >> 6, lane = tid & 63;
    const int wr   = (wave >> 1) * 64, wc = (wave & 1) * 64;
    const int r    = lane & 15, g = lane >> 4;
    fx4 acc[4][4] = {};

    s16x8 a_h[2][4], a_l[2][4];
#pragma unroll
    for (int i = 0; i < 4; ++i) {
        const size_t off = (size_t)(wr + i*16 + r) * H_ + kbeg + g*8;
        a_h[0][i] = ald_s16x8(Agh + off);
        a_l[0][i] = ald_s16x8(Agl + off);
    }
    for (int kt = 0; kt < 8; ++kt) {
        const int cur = kt & 1, nxt = cur ^ 1;
        if (kt < 7) {
#pragma unroll
            for (int i = 0; i < 4; ++i) {
                const size_t off = (size_t)(wr + i*16 + r) * H_ + kbeg + (kt+1)*32 + g*8;
                a_h[nxt][i] = ald_s16x8(Agh + off);
                a_l[nxt][i] = ald_s16x8(Agl + off);
            }
        }
        s16x8 b_h[4], b_l[4];
#pragma unroll
        for (int j = 0; j < 4; ++j) {
            const int bo = (kt*128 + (wc + j*16 + r))*32 + g*8;
            b_h[j] = *(const s16x8*)&sWh[bo];
            b_l[j] = *(const s16x8*)&sWl[bo];
        }
#pragma unroll
        for (int i = 0; i < 4; ++i)
#pragma unroll
            for (int j = 0; j < 4; ++j) {
                acc[i][j] = __builtin_amdgcn_mfma_f32_16x16x32_bf16(a_h[cur][i], b_h[j], acc[i][j], 0, 0, 0);
                acc[i][j] = __builtin_amdgcn_mfma_f32_16x16x32_bf16(a_l[cur][i], b_h[j], acc[i][j], 0, 0, 0);
                acc[i][j] = __builtin_amdgcn_mfma_f32_16x16x32_bf16(a_h[cur][i], b_l[j], acc[i][j], 0, 0, 0);
            }
    }
    cwrite_at(acc, Cw, ldc, colbase, wr, wc, r, g);
}

// C2-phase job: A (activations) via sc1, W (read-only weights) via plain loads (L2-resident).
__device__ __forceinline__ void job_stream(
    const ushort_t* __restrict__ Agh, const ushort_t* __restrict__ Agl,
    const ushort_t* __restrict__ Wgh, const ushort_t* __restrict__ Wgl,
    int kbeg, float* __restrict__ Cw, int ldc, int colbase)
{
    const int tid  = threadIdx.x;
    const int wave = tid >> 6, lane = tid & 63;
    const int wr   = (wave >> 1) * 64, wc = (wave & 1) * 64;
    const int r    = lane & 15, g = lane >> 4;
    fx4 acc[4][4] = {};

    s16x8 a_h[2][4], a_l[2][4], b_h[2][4], b_l[2][4];
#pragma unroll
    for (int i = 0; i < 4; ++i) {
        const size_t aoff = (size_t)(wr + i*16 + r) * H_ + kbeg + g*8;
        const size_t boff = (size_t)(wc + i*16 + r) * H_ + kbeg + g*8;
        a_h[0][i] = ald_s16x8(Agh + aoff);
        a_l[0][i] = ald_s16x8(Agl + aoff);
        b_h[0][i] = *(const s16x8*)(Wgh + boff);
        b_l[0][i] = *(const s16x8*)(Wgl + boff);
    }
    for (int kt = 0; kt < 8; ++kt) {
        const int cur = kt & 1, nxt = cur ^ 1;
        if (kt < 7) {
#pragma unroll
            for (int i = 0; i < 4; ++i) {
                const size_t aoff = (size_t)(wr + i*16 + r) * H_ + kbeg + (kt+1)*32 + g*8;
                const size_t boff = (size_t)(wc + i*16 + r) * H_ + kbeg + (kt+1)*32 + g*8;
                a_h[nxt][i] = ald_s16x8(Agh + aoff);
                a_l[nxt][i] = ald_s16x8(Agl + aoff);
                b_h[nxt][i] = *(const s16x8*)(Wgh + boff);
                b_l[nxt][i] = *(const s16x8*)(Wgl + boff);
            }
        }
#pragma unroll
        for (int i = 0; i < 4; ++i)
#pragma unroll
            for (int j = 0; j < 4; ++j) {
                acc[i][j] = __builtin_amdgcn_mfma_f32_16x16x32_bf16(a_h[cur][i], b_h[cur][j], acc[i][j], 0, 0, 0);
                acc[i][j] = __builtin_amdgcn_mfma_f32_16x16x32_bf16(a_l[cur][i], b_h[cur][j], acc[i][j], 0, 0, 0);
                acc[i][j] = __builtin_amdgcn_mfma_f32_16x16x32_bf16(a_h[cur][i], b_l[cur][j], acc[i][j], 0, 0, 0);
            }
    }
    cwrite_at(acc, Cw, ldc, colbase, wr, wc, r, g);
}

// Two-level grid barrier, ALL RELAXED (no acquire-inv, no release-wbl2).
// Correctness: all cross-block data moves via sc1 (L2-bypass) atomics, so no
// cache invalidation is needed; __syncthreads' vmcnt(0) drains the sc1 stores
// before lane0 signals arrival. Round 4/5's acquire-per-poll buffer_inv was
// the 20x slowdown (measured: 268 GB/s HBM of weight refetch, MfmaUtil 1.1%).
__device__ __forceinline__ void gbar(int* bar, int* lg) {
    __syncthreads();
    if (threadIdx.x == 0) {
        const int g = *lg;
        const int grp = blockIdx.x >> 4;          // 16 groups x 16 blocks
        const int p1 = __hip_atomic_fetch_add(&bar[grp*16], 1, __ATOMIC_RELAXED,
                                              __HIP_MEMORY_SCOPE_AGENT);
        if (p1 == 15) {
            const int p2 = __hip_atomic_fetch_add(&bar[BAR_MASTER], 1, __ATOMIC_RELAXED,
                                                  __HIP_MEMORY_SCOPE_AGENT);
            if (p2 == 15) {
                for (int g2 = 0; g2 < 16; ++g2)
                    __hip_atomic_store(&bar[g2*16], 0, __ATOMIC_RELAXED, __HIP_MEMORY_SCOPE_AGENT);
                __hip_atomic_store(&bar[BAR_MASTER], 0, __ATOMIC_RELAXED, __HIP_MEMORY_SCOPE_AGENT);
                __hip_atomic_store(&bar[BAR_GEN], g + 1, __ATOMIC_RELAXED, __HIP_MEMORY_SCOPE_AGENT);
            } else {
                while (__hip_atomic_load(&bar[BAR_GEN], __ATOMIC_RELAXED,
                                         __HIP_MEMORY_SCOPE_AGENT) == g)
                    __builtin_amdgcn_s_sleep(2);
            }
        } else {
            while (__hip_atomic_load(&bar[BAR_GEN], __ATOMIC_RELAXED,
                                     __HIP_MEMORY_SCOPE_AGENT) == g)
                __builtin_amdgcn_s_sleep(2);
        }
        *lg = g + 1;
    }
    __syncthreads();
}

// pairized decoder-GRU update (2 consecutive elems per thread)
__device__ __forceinline__ void dec_update2(int base,
    const float* __restrict__ gi2p, const float* __restrict__ gh2p,
    const float* __restrict__ dec_bih, const float* __restrict__ dec_bhh,
    float* __restrict__ dh, ushort_t* __restrict__ dhh, ushort_t* __restrict__ dhl)
{
    const int b = base >> 10, j = base & (H_ - 1);
    float2 ir = *(const float2*)&dec_bih[j];
    float2 iz = *(const float2*)&dec_bih[H_+j];
    float2 in2 = *(const float2*)&dec_bih[2*H_+j];
    const float* p = gi2p + (size_t)b * G3;
#pragma unroll
    for (int s2 = 0; s2 < KSPLIT; ++s2) {
        float2 a0 = u2f2(ald64(&p[j]));      ir.x += a0.x; ir.y += a0.y;
        float2 a1 = u2f2(ald64(&p[H_+j]));   iz.x += a1.x; iz.y += a1.y;
        float2 a2 = u2f2(ald64(&p[2*H_+j])); in2.x += a2.x; in2.y += a2.y;
        p += (size_t)B_ * G3;
    }
    float2 hr = *(const float2*)&dec_bhh[j];
    float2 hz = *(const float2*)&dec_bhh[H_+j];
    float2 hn = *(const float2*)&dec_bhh[2*H_+j];
    const float* q = gh2p + (size_t)b * G3;
#pragma unroll
    for (int s2 = 0; s2 < KSPLIT; ++s2) {
        float2 a0 = u2f2(ald64(&q[j]));      hr.x += a0.x; hr.y += a0.y;
        float2 a1 = u2f2(ald64(&q[H_+j]));   hz.x += a1.x; hz.y += a1.y;
        float2 a2 = u2f2(ald64(&q[2*H_+j])); hn.x += a2.x; hn.y += a2.y;
        q += (size_t)B_ * G3;
    }
    float2 old = *(const float2*)&dh[base];
    const float v0 = gru_elem(ir.x, iz.x, in2.x, hr.x, hz.x, hn.x, old.x);
    const float v1 = gru_elem(ir.y, iz.y, in2.y, hr.y, hz.y, hn.y, old.y);
    *(float2*)&dh[base] = make_float2(v0, v1);
    ushort_t h0,l0,h1,l1;
    split1(v0,h0,l0); split1(v1,h1,l1);
    ast32(&dhh[base], (unsigned)h0 | ((unsigned)h1 << 16));
    ast32(&dhl[base], (unsigned)l0 | ((unsigned)l1 << 16));
}

// ---------------- persistent weight-stationary encoder scan ----------------
__global__ __launch_bounds__(256) void enc_persist(
    const float* __restrict__ gi,
    const ushort_t* __restrict__ Whh_h, const ushort_t* __restrict__ Whh_l,
    const ushort_t* __restrict__ l1h,   const ushort_t* __restrict__ l1l,
    const ushort_t* __restrict__ dWih_h,const ushort_t* __restrict__ dWih_l,
    const ushort_t* __restrict__ dWhh_h,const ushort_t* __restrict__ dWhh_l,
    const float* __restrict__ enc_bhh,  const float* __restrict__ lin1_b,
    const float* __restrict__ dec_bih,  const float* __restrict__ dec_bhh,
    float* __restrict__ eh, ushort_t* __restrict__ ehh, ushort_t* __restrict__ ehl,
    float* __restrict__ dh, ushort_t* __restrict__ dhh, ushort_t* __restrict__ dhl,
    ushort_t* __restrict__ uh, ushort_t* __restrict__ ul,
    float* __restrict__ ghp, float* __restrict__ up,
    float* __restrict__ gi2p, float* __restrict__ gh2p,
    int* __restrict__ bar)
{
    extern __shared__ ushort_t smw[];     // 128 KiB: [0,32768) hi, [32768,65536) lo
    ushort_t* sWh = smw;
    ushort_t* sWl = smw + 32768;

    const int bid = blockIdx.x;
    const int tid = threadIdx.x;
    int lg = 0;

    // one-time: resident phase-B weight tile into LDS (weights are read-only,
    // written before this launch -> plain loads, always coherent)
    if (bid < 224) {
        const ushort_t *Wh, *Wl; int ldw, rowbase, kbeg0;
        if (bid < 96)       { const int jj=bid;     Wh=Whh_h;  Wl=Whh_l;  ldw=H_;   rowbase=(jj>>2)*128; kbeg0=(jj&3)*256; }
        else if (bid < 128) { const int jj=bid-96;  Wh=l1h;    Wl=l1l;    ldw=2*H_; rowbase=(jj>>2)*128; kbeg0=(jj&3)*256; }
        else                { const int jj=bid-128; Wh=dWhh_h; Wl=dWhh_l; ldw=H_;   rowbase=(jj>>2)*128; kbeg0=(jj&3)*256; }
        for (int c = tid; c < 4096; c += 256) {
            const int row  = c >> 5;
            const int col8 = (c & 31) * 8;
            const int kt = col8 >> 5, kk = col8 & 31;
            const size_t goff = (size_t)(rowbase + row) * ldw + kbeg0 + col8;
            const int    loff = (kt*128 + row)*32 + kk;
            *(s16x8*)&sWh[loff] = *(const s16x8*)(Wh + goff);
            *(s16x8*)&sWl[loff] = *(const s16x8*)(Wl + goff);
        }
    }
    __syncthreads();

    for (int t = 0; t < T_; ++t) {
        // ---- phase A: eh <- GRU(gi[t], ghp) ; dh <- GRU(gi2p, gh2p) [lagged] ----
        {
            const int base = bid * 512 + tid * 2;         // covers B_*H_
            const int b = base >> 10, j = base & (H_ - 1);
            const float* girow = gi + ((size_t)(b * T_ + t)) * G3;
            float2 ir = *(const float2*)&girow[j];
            float2 iz = *(const float2*)&girow[H_+j];
            float2 in2 = *(const float2*)&girow[2*H_+j];
            float2 hr = *(const float2*)&enc_bhh[j];
            float2 hz = *(const float2*)&enc_bhh[H_+j];
            float2 hn = *(const float2*)&enc_bhh[2*H_+j];
            const float* q = ghp + (size_t)b * G3;
#pragma unroll
            for (int s2 = 0; s2 < KSPLIT; ++s2) {
                float2 a0 = u2f2(ald64(&q[j]));      hr.x += a0.x; hr.y += a0.y;
                float2 a1 = u2f2(ald64(&q[H_+j]));   hz.x += a1.x; hz.y += a1.y;
                float2 a2 = u2f2(ald64(&q[2*H_+j])); hn.x += a2.x; hn.y += a2.y;
                q += (size_t)B_ * G3;
            }
            float2 old = *(const float2*)&eh[base];
            const float v0 = gru_elem(ir.x, iz.x, in2.x, hr.x, hz.x, hn.x, old.x);
            const float v1 = gru_elem(ir.y, iz.y, in2.y, hr.y, hz.y, hn.y, old.y);
            *(float2*)&eh[base] = make_float2(v0, v1);
            ushort_t h0,l0,h1,l1;
            split1(v0,h0,l0); split1(v1,h1,l1);
            ast32(&ehh[base], (unsigned)h0 | ((unsigned)h1 << 16));
            ast32(&ehl[base], (unsigned)l0 | ((unsigned)l1 << 16));
            if (t > 0)
                dec_update2(base, gi2p, gh2p, dec_bih, dec_bhh, dh, dhh, dhl);
        }
        gbar(bar, &lg);

        // ---- phase B (resident weights): ghp / up / gh2p ----
        if (bid < 96) {
            const int ntile = bid >> 2, kc = bid & 3;
            job_resB(ehh, ehl, sWh, sWl, kc*256,
                     ghp + (size_t)kc * B_ * G3, G3, ntile * 128);
        } else if (bid < 128) {
            const int jj = bid - 96, ntile = jj >> 2, kc = jj & 3;
            job_resB(ehh, ehl, sWh, sWl, kc*256,
                     up + (size_t)kc * B_ * H_, H_, ntile * 128);
        } else if (bid < 224) {
            const int jj = bid - 128, ntile = jj >> 2, kc = jj & 3;
            job_resB(dhh, dhl, sWh, sWl, kc*256,
                     gh2p + (size_t)kc * B_ * G3, G3, ntile * 128);
        }
        gbar(bar, &lg);

        // ---- phase C1: u <- relu(sum up + lin1_b), split ----
        {
            const int base = bid * 512 + tid * 2;
            const int j = base & (H_ - 1);
            float2 v = *(const float2*)&lin1_b[j];
#pragma unroll
            for (int s2 = 0; s2 < KSPLIT; ++s2) {
                float2 a = u2f2(ald64(&up[(size_t)s2 * B_ * H_ + base]));
                v.x += a.x; v.y += a.y;
            }
            v.x = fmaxf(v.x, 0.f); v.y = fmaxf(v.y, 0.f);
            ushort_t h0,l0,h1,l1;
            split1(v.x,h0,l0); split1(v.y,h1,l1);
            ast32(&uh[base], (unsigned)h0 | ((unsigned)h1 << 16));
            ast32(&ul[base], (unsigned)l0 | ((unsigned)l1 << 16));
        }
        gbar(bar, &lg);

        // ---- phase C2 (streamed dWih, plain loads -> stays L2-resident): gi2p ----
        if (bid < 96) {
            const int ntile = bid >> 2, kc = bid & 3;
            job_stream(uh, ul,
                       dWih_h + (size_t)ntile * 128 * H_,
                       dWih_l + (size_t)ntile * 128 * H_,
                       kc * 256,
                       gi2p + (size_t)kc * B_ * G3, G3, ntile * 128);
        }
        gbar(bar, &lg);
    }

    // tail: finish dec GRU of step T-1
    {
        const int base = bid * 512 + tid * 2;
        dec_update2(base, gi2p, gh2p, dec_bih, dec_bhh, dh, dhh, dhl);
    }
}

// ---------------- decoder elementwise kernels (separate launches: plain ops OK) ----------------
__global__ __launch_bounds__(256) void gru_update2(
    const float* __restrict__ GI, int gi_rstride, int gi_nsplit,
    const float* __restrict__ bih,
    const float* __restrict__ GHp, const float* __restrict__ bhh,
    float* __restrict__ h, ushort_t* __restrict__ hh, ushort_t* __restrict__ hl)
{
    const int idx = blockIdx.x * 256 + threadIdx.x;
    const int b = idx >> 10;
    const int j = idx & (H_ - 1);
    float ir, iz, inn;
    if (gi_nsplit == 0) {
        const float* gi = GI + (size_t)b * gi_rstride;
        ir = gi[j]; iz = gi[H_ + j]; inn = gi[2*H_ + j];
    } else {
        ir = bih[j]; iz = bih[H_ + j]; inn = bih[2*H_ + j];
        const float* p = GI + (size_t)b * G3;
#pragma unroll
        for (int s = 0; s < KSPLIT; ++s) {
            ir += p[j]; iz += p[H_ + j]; inn += p[2*H_ + j];
            p += (size_t)B_ * G3;
        }
    }
    float hr = bhh[j], hz = bhh[H_ + j], hn = bhh[2*H_ + j];
    const float* q = GHp + (size_t)b * G3;
#pragma unroll
    for (int s = 0; s < KSPLIT; ++s) {
        hr += q[j]; hz += q[H_ + j]; hn += q[2*H_ + j];
        q += (size_t)B_ * G3;
    }
    const float v = gru_elem(ir, iz, inn, hr, hz, hn, h[idx]);
    h[idx] = v;
    split1(v, hh[idx], hl[idx]);
}

__global__ __launch_bounds__(256) void relu_combine(
    const float* __restrict__ Up, const float* __restrict__ bias,
    ushort_t* __restrict__ uh, ushort_t* __restrict__ ul)
{
    const int idx = blockIdx.x * 256 + threadIdx.x;
    const int j = idx & (H_ - 1);
    float v = bias[j];
#pragma unroll
    for (int s = 0; s < KSPLIT; ++s) v += Up[(size_t)s * B_ * H_ + idx];
    v = fmaxf(v, 0.f);
    split1(v, uh[idx], ul[idx]);
}

__global__ __launch_bounds__(256) void cat_eh_emb(
    const ushort_t* __restrict__ ehh, const ushort_t* __restrict__ ehl,
    const float* __restrict__ embed, const int* __restrict__ word,
    ushort_t* __restrict__ cath, ushort_t* __restrict__ catl)
{
    const int idx = blockIdx.x * 256 + threadIdx.x;
    const int b = idx >> 11;
    const int j = idx & (2*H_ - 1);
    if (j < H_) {
        cath[idx] = ehh[b * H_ + j];
        catl[idx] = ehl[b * H_ + j];
    } else {
        float v = embed[(size_t)word[b] * H_ + (j - H_)];
        split1(v, cath[idx], catl[idx]);
    }
}

// ---------------- init ----------------
__global__ __launch_bounds__(256) void init_state(
    float* __restrict__ eh, float* __restrict__ dh,
    ushort_t* __restrict__ ehh, ushort_t* __restrict__ ehl,
    ushort_t* __restrict__ dhh, ushort_t* __restrict__ dhl,
    int* __restrict__ word, float* __restrict__ out,
    float* __restrict__ ghp, int* __restrict__ bar)
{
    const int idx = blockIdx.x * 256 + threadIdx.x;
    if (idx < KSPLIT*B_*G3) ghp[idx] = 0.f;
    if (idx < B_*H_) {
        eh[idx] = 0.f; dh[idx] = 0.f;
        ehh[idx] = 0; ehl[idx] = 0; dhh[idx] = 0; dhl[idx] = 0;
    }
    if (idx < B_)   word[idx] = 1;
    if (idx < 21)   out[idx] = 0.f;
    if (idx < 512)  bar[idx] = 0;
}

// ---------------- log-softmax + argmax + loss over 2 logit partials ----------------
__global__ __launch_bounds__(256) void softmax_loss(
    const float* __restrict__ logp, const float* __restrict__ l2b,
    const int* __restrict__ target, int s, int* __restrict__ word,
    float* __restrict__ out)
{
    const int b = blockIdx.x;
    const int t = threadIdx.x;
    const float* p0 = logp + (size_t)b * VP;
    const float* p1 = p0 + (size_t)B_ * VP;
    __shared__ float sv[256];
    __shared__ int   si[256];
    __shared__ float ss[256];

    float best = -FLT_MAX; int bi = 0;
    for (int j = t; j < V_; j += 256) {
        float v = p0[j] + p1[j] + l2b[j];
        if (v > best) { best = v; bi = j; }
    }
    sv[t] = best; si[t] = bi;
    __syncthreads();
    for (int off = 128; off > 0; off >>= 1) {
        if (t < off) {
            float v2 = sv[t + off]; int i2 = si[t + off];
            if (v2 > sv[t] || (v2 == sv[t] && i2 < si[t])) { sv[t] = v2; si[t] = i2; }
        }
        __syncthreads();
    }
    const float m = sv[0];
    const int amax = si[0];

    float sum = 0.f;
    for (int j = t; j < V_; j += 256) sum += expf(p0[j] + p1[j] + l2b[j] - m);
    ss[t] = sum;
    __syncthreads();
    for (int off = 128; off > 0; off >>= 1) {
        if (t < off) ss[t] += ss[t + off];
        __syncthreads();
    }
    if (t == 0) {
        const float lse = m + logf(ss[0]);
        const int tgt = target[b * S_ + s];
        const float logit_t = p0[tgt] + p1[tgt] + l2b[tgt];
        atomicAdd(&out[0], -(logit_t - lse) * (1.0f / (float)B_));
        word[b] = amax;
        if (b == 0) out[1 + s]  = (float)amax;
        if (b == 1) out[11 + s] = (float)amax;
    }
}

// ---------------- host helpers ----------------
static inline void launch_x3(hipStream_t st,
    const ushort_t* Ah, const ushort_t* Al, int lda,
    const ushort_t* Bh, const ushort_t* Bl, int ldw,
    const float* bias, float* C, int M, int N, int K, int kchunks)
{
    dim3 grid(N/128, M/128, kchunks);
    gemm_x3<<<grid, 256, 0, st>>>(Ah, Al, lda, Bh, Bl, ldw, bias, C, M, N, K, kchunks,
                                  nullptr, nullptr, nullptr, nullptr, nullptr);
}

static inline void launch_x3_dual(hipStream_t st,
    const ushort_t* Ah, const ushort_t* Al,
    const ushort_t* Bh, const ushort_t* Bl, float* C,
    const ushort_t* A2h, const ushort_t* A2l,
    const ushort_t* B2h, const ushort_t* B2l, float* C2,
    int M, int N, int K, int kchunks)
{
    dim3 grid(N/128, M/128, 2*kchunks);
    gemm_x3<<<grid, 256, 0, st>>>(Ah, Al, H_, Bh, Bl, H_, nullptr, C, M, N, K, kchunks,
                                  A2h, A2l, B2h, B2l, C2);
}

extern "C" void kernel_launch(void* const* d_in, const int* in_sizes, int n_in,
                              void* d_out, int out_size, void* d_ws, size_t ws_size,
                              hipStream_t stream)
{
    const float* data    = (const float*)d_in[0];
    const int*   target  = (const int*)  d_in[2];
    const float* enc_Wih = (const float*)d_in[4];
    const float* enc_Whh = (const float*)d_in[5];
    const float* enc_bih = (const float*)d_in[6];
    const float* enc_bhh = (const float*)d_in[7];
    const float* dec_Wih = (const float*)d_in[8];
    const float* dec_Whh = (const float*)d_in[9];
    const float* dec_bih = (const float*)d_in[10];
    const float* dec_bhh = (const float*)d_in[11];
    const float* lin1_W  = (const float*)d_in[12];
    const float* lin1_b  = (const float*)d_in[13];
    const float* lin2_W  = (const float*)d_in[14];
    const float* lin2_b  = (const float*)d_in[15];
    const float* embed   = (const float*)d_in[16];
    float* out = (float*)d_out;

    float *gi, *eh, *dh, *logitsp, *ghp, *gi2p, *gh2p, *up;
    ushort_t *Ah, *Al, *Bh, *Bl, *Whh_h, *Whh_l, *dWih_h, *dWih_l, *dWhh_h, *dWhh_l;
    ushort_t *l1h, *l1l, *l2h, *l2l, *ehh, *ehl, *dhh, *dhl, *uh, *ul, *cath, *catl;
    int *word, *bar;
    hipGetSymbolAddress((void**)&gi,     HIP_SYMBOL(g_gi));
    hipGetSymbolAddress((void**)&Ah,     HIP_SYMBOL(g_Ah));
    hipGetSymbolAddress((void**)&Al,     HIP_SYMBOL(g_Al));
    hipGetSymbolAddress((void**)&Bh,     HIP_SYMBOL(g_Bh));
    hipGetSymbolAddress((void**)&Bl,     HIP_SYMBOL(g_Bl));
    hipGetSymbolAddress((void**)&Whh_h,  HIP_SYMBOL(g_Whh_h));
    hipGetSymbolAddress((void**)&Whh_l,  HIP_SYMBOL(g_Whh_l));
    hipGetSymbolAddress((void**)&dWih_h, HIP_SYMBOL(g_dWih_h));
    hipGetSymbolAddress((void**)&dWih_l, HIP_SYMBOL(g_dWih_l));
    hipGetSymbolAddress((void**)&dWhh_h, HIP_SYMBOL(g_dWhh_h));
    hipGetSymbolAddress((void**)&dWhh_l, HIP_SYMBOL(g_dWhh_l));
    hipGetSymbolAddress((void**)&l1h,    HIP_SYMBOL(g_l1h));
    hipGetSymbolAddress((void**)&l1l,    HIP_SYMBOL(g_l1l));
    hipGetSymbolAddress((void**)&l2h,    HIP_SYMBOL(g_l2h));
    hipGetSymbolAddress((void**)&l2l,    HIP_SYMBOL(g_l2l));
    hipGetSymbolAddress((void**)&ghp,    HIP_SYMBOL(g_ghp));
    hipGetSymbolAddress((void**)&gi2p,   HIP_SYMBOL(g_gi2p));
    hipGetSymbolAddress((void**)&gh2p,   HIP_SYMBOL(g_gh2p));
    hipGetSymbolAddress((void**)&up,     HIP_SYMBOL(g_up));
    hipGetSymbolAddress((void**)&eh,     HIP_SYMBOL(g_eh));
    hipGetSymbolAddress((void**)&dh,     HIP_SYMBOL(g_dh));
    hipGetSymbolAddress((void**)&ehh,    HIP_SYMBOL(g_ehh));
    hipGetSymbolAddress((void**)&ehl,    HIP_SYMBOL(g_ehl));
    hipGetSymbolAddress((void**)&dhh,    HIP_SYMBOL(g_dhh));
    hipGetSymbolAddress((void**)&dhl,    HIP_SYMBOL(g_dhl));
    hipGetSymbolAddress((void**)&uh,     HIP_SYMBOL(g_uh));
    hipGetSymbolAddress((void**)&ul,     HIP_SYMBOL(g_ul));
    hipGetSymbolAddress((void**)&cath,   HIP_SYMBOL(g_cath));
    hipGetSymbolAddress((void**)&catl,   HIP_SYMBOL(g_catl));
    hipGetSymbolAddress((void**)&logitsp,HIP_SYMBOL(g_logitsp));
    hipGetSymbolAddress((void**)&word,   HIP_SYMBOL(g_word));
    hipGetSymbolAddress((void**)&bar,    HIP_SYMBOL(g_bar));

    hipFuncSetAttribute((const void*)enc_persist,
                        hipFuncAttributeMaxDynamicSharedMemorySize, 131072);

    init_state<<<6144, 256, 0, stream>>>(eh, dh, ehh, ehl, dhh, dhl, word, out, ghp, bar);

    // bf16 hi/lo splits
    split_bf16<<<(B_*T_*D_/4 + 255)/256, 256, 0, stream>>>(data,    Ah, Al, B_*T_*D_/4);
    split_bf16<<<(G3*D_/4   + 255)/256, 256, 0, stream>>>(enc_Wih, Bh, Bl, G3*D_/4);
    split_bf16<<<(G3*H_/4   + 255)/256, 256, 0, stream>>>(enc_Whh, Whh_h, Whh_l, G3*H_/4);
    split_bf16<<<(G3*H_/4   + 255)/256, 256, 0, stream>>>(dec_Wih, dWih_h, dWih_l, G3*H_/4);
    split_bf16<<<(G3*H_/4   + 255)/256, 256, 0, stream>>>(dec_Whh, dWhh_h, dWhh_l, G3*H_/4);
    split_bf16<<<(H_*2*H_/4 + 255)/256, 256, 0, stream>>>(lin1_W,  l1h, l1l, H_*2*H_/4);
    split_bf16<<<(V_*H_/4   + 255)/256, 256, 0, stream>>>(lin2_W,  l2h, l2l, V_*H_/4);

    // gi[B*T][3H] = data @ enc_Wih^T + enc_bih
    launch_x3(stream, Ah, Al, D_, Bh, Bl, D_, enc_bih, gi, B_*T_, G3, D_, 1);

    // ---------------- encoder scan: ONE persistent launch ----------------
    enc_persist<<<NBLK, 256, 131072, stream>>>(
        gi, Whh_h, Whh_l, l1h, l1l, dWih_h, dWih_l, dWhh_h, dWhh_l,
        enc_bhh, lin1_b, dec_bih, dec_bhh,
        eh, ehh, ehl, dh, dhh, dhl, uh, ul,
        ghp, up, gi2p, gh2p, bar);

    // ---------------- decoder scan ----------------
    for (int s = 0; s < S_; ++s) {
        launch_x3(stream, ehh, ehl, H_, Whh_h, Whh_l, H_, nullptr, ghp, B_, G3, H_, KSPLIT);
        gru_update2<<<512, 256, 0, stream>>>(enc_bih, 0, 0, nullptr,
                                             ghp, enc_bhh, eh, ehh, ehl);
        cat_eh_emb<<<1024, 256, 0, stream>>>(ehh, ehl, embed, word, cath, catl);
        launch_x3(stream, cath, catl, 2*H_, l1h, l1l, 2*H_, nullptr, up, B_, H_, 2*H_, KSPLIT);
        relu_combine<<<512, 256, 0, stream>>>(up, lin1_b, uh, ul);
        launch_x3_dual(stream, uh, ul, dWih_h, dWih_l, gi2p,
                               dhh, dhl, dWhh_h, dWhh_l, gh2p, B_, G3, H_, KSPLIT);
        gru_update2<<<512, 256, 0, stream>>>(gi2p, 0, KSPLIT, dec_bih,
                                             gh2p, dec_bhh, dh, dhh, dhl);
        launch_x3(stream, dhh, dhl, H_, l2h, l2l, H_, nullptr, logitsp, B_, VP, H_, 2);
        softmax_loss<<<B_, 256, 0, stream>>>(logitsp, lin2_b, target, s, word, out);
    }
}